// Round 4
// baseline (51.351 us; speedup 1.0000x reference)
//
#include <hip/hip_runtime.h>
#include <math.h>

#define N_USERS 200000
#define N_ITEMS 200000
#define HOPS 4
#define DIM 64
#define BATCH 2048
#define N_NEGS 64
#define KK 2
#define ROW 256          // HOPS*DIM
#define DECAY 0.0001f

// One block per batch element. 256 threads = 4 waves.
// Candidate rows are streamed global->LDS via global_load_lds DMA, 4-deep
// ring per wave, counted vmcnt(3) waits (never 0 in the loop). Each lane
// then reads only its own 16B fragment from LDS (1 ds_read_b128).
// c = 0..31 enumerates candidates: k = c&1 (alternating streams), i = c>>1,
// n = (i<<2)+w  -> per-k processing order is i-ascending (argmax-first ties
// preserved; ties only arise from duplicate item ids -> identical rows).
__global__ __launch_bounds__(256, 8) void mixgcf_main(
    const float* __restrict__ user_emb,
    const float* __restrict__ item_emb,
    const float* __restrict__ seed_embed,
    const int*   __restrict__ user,
    const int*   __restrict__ pos_item,
    const int*   __restrict__ neg_item,
    float*       __restrict__ ws)
{
    const int b    = blockIdx.x;
    const int tid  = threadIdx.x;
    const int w    = tid >> 6;     // wave id 0..3
    const int lane = tid & 63;

    __shared__ float ring[4][4][ROW];     // [wave][slot][1KB row]
    __shared__ int   nidx[KK * N_NEGS];   // 128 candidate indices
    __shared__ float selv[KK][ROW];       // selected mixed rows
    __shared__ float scw[KK][4][HOPS];    // per-wave best score per hop

    const int   uidx = user[b];
    const int   pidx = pos_item[b];
    const float seed = seed_embed[b];

    if (tid < KK * N_NEGS) nidx[tid] = neg_item[(size_t)b * (KK * N_NEGS) + tid];
    __syncthreads();

    // Per-lane user/pos fragments; computing sp forces the vmcnt waits for
    // these loads to retire BEFORE the DMA prologue (sched_barrier pins it).
    const float4 s4 = *(const float4*)(user_emb + (size_t)uidx * ROW + lane * 4);
    const float4 p4 = *(const float4*)(item_emb + (size_t)pidx * ROW + lane * 4);
    const float  omse = 1.0f - seed;
    const float4 sp = make_float4(seed * p4.x, seed * p4.y, seed * p4.z, seed * p4.w);
    const int h = lane >> 4;   // hop this lane's 16-group owns
    __builtin_amdgcn_sched_barrier(0);

    // Issue one candidate row (1KB) into ring[w][slot]: per-lane global src,
    // wave-uniform LDS base, HW writes lds_base + lane*16 (linear).
    auto issue = [&](int cc, int slot) {
        const int k  = cc & 1;
        const int i  = cc >> 1;
        const int it = nidx[k * N_NEGS + (i << 2) + w];   // wave-uniform
        const float* src = item_emb + (size_t)it * ROW + lane * 4;
        __builtin_amdgcn_global_load_lds(
            (const __attribute__((address_space(1))) void*)src,
            (__attribute__((address_space(3))) void*)&ring[w][slot][0],
            16, 0, 0);
    };

    // Prologue: rows 0..3 -> slots 0..3 (vmcnt = 4 outstanding)
    issue(0, 0); issue(1, 1); issue(2, 2); issue(3, 3);

    float  best0 = -INFINITY, best1 = -INFINITY;
    float4 bv0 = make_float4(0.f, 0.f, 0.f, 0.f);
    float4 bv1 = make_float4(0.f, 0.f, 0.f, 0.f);

    #pragma unroll 4
    for (int c = 0; c < 32; ++c) {
        if (c > 0) {
            // Slot (c-1)&3 was consumed last iteration; its ds_read has
            // retired (data already used), so this lgkmcnt(0) is ~free.
            asm volatile("s_waitcnt lgkmcnt(0)" ::: "memory");
            __builtin_amdgcn_sched_barrier(0);
            const int cc = (c + 3 < 32) ? (c + 3) : 31;   // tail: dummy reload
            issue(cc, (c - 1) & 3);                       // keeps vmcnt math constant
        }
        // issued = c+4 (+const prelude); wait vmcnt(3) => rows 0..c complete.
        asm volatile("s_waitcnt vmcnt(3)" ::: "memory");
        __builtin_amdgcn_sched_barrier(0);

        const int slot = c & 3;
        const float4 ne = *(const float4*)&ring[w][slot][lane * 4];

        float4 m;
        m.x = fmaf(omse, ne.x, sp.x);
        m.y = fmaf(omse, ne.y, sp.y);
        m.z = fmaf(omse, ne.z, sp.z);
        m.w = fmaf(omse, ne.w, sp.w);

        float sc = m.x * s4.x;
        sc = fmaf(m.y, s4.y, sc);
        sc = fmaf(m.z, s4.z, sc);
        sc = fmaf(m.w, s4.w, sc);
        sc += __shfl_xor(sc, 1);
        sc += __shfl_xor(sc, 2);
        sc += __shfl_xor(sc, 4);
        sc += __shfl_xor(sc, 8);

        if ((c & 1) == 0) { if (sc > best0) { best0 = sc; bv0 = m; } }
        else              { if (sc > best1) { best1 = sc; bv1 = m; } }
    }

    // cross-wave argmax per (k, hop)
    if ((lane & 15) == 0) { scw[0][w][h] = best0; scw[1][w][h] = best1; }
    __syncthreads();   // also drains the 3 tail dummy DMAs
    {
        float a0 = scw[0][0][h], a1 = scw[0][1][h], a2 = scw[0][2][h], a3 = scw[0][3][h];
        int win0 = 0; float mb = a0;
        if (a1 > mb) { mb = a1; win0 = 1; }
        if (a2 > mb) { mb = a2; win0 = 2; }
        if (a3 > mb) { mb = a3; win0 = 3; }
        if (w == win0) *(float4*)(&selv[0][lane * 4]) = bv0;

        float c0 = scw[1][0][h], c1 = scw[1][1][h], c2 = scw[1][2][h], c3 = scw[1][3][h];
        int win1 = 0; float nb = c0;
        if (c1 > nb) { nb = c1; win1 = 1; }
        if (c2 > nb) { nb = c2; win1 = 2; }
        if (c3 > nb) { nb = c3; win1 = 3; }
        if (w == win1) *(float4*)(&selv[1][lane * 4]) = bv1;
    }
    __syncthreads();

    // Epilogue: wave 0, lane c = channel (user/pos rows are cache-hot)
    if (w == 0) {
        const int c = lane;
        const float* ur = user_emb + (size_t)uidx * ROW;
        const float* pr = item_emb + (size_t)pidx * ROW;
        const float ue = 0.25f * (ur[c] + ur[64 + c] + ur[128 + c] + ur[192 + c]);
        const float pe = 0.25f * (pr[c] + pr[64 + c] + pr[128 + c] + pr[192 + c]);
        const float n0 = 0.25f * (selv[0][c] + selv[0][64 + c] + selv[0][128 + c] + selv[0][192 + c]);
        const float n1 = 0.25f * (selv[1][c] + selv[1][64 + c] + selv[1][128 + c] + selv[1][192 + c]);
        float ps  = ue * pe;
        float ns0 = ue * n0;
        float ns1 = ue * n1;
        float rg  = ue * ue + pe * pe + n0 * n0 + n1 * n1;
        #pragma unroll
        for (int m = 1; m < 64; m <<= 1) {
            ps  += __shfl_xor(ps,  m);
            ns0 += __shfl_xor(ns0, m);
            ns1 += __shfl_xor(ns1, m);
            rg  += __shfl_xor(rg,  m);
        }
        if (lane == 0) {
            const float mf = log1pf(expf(ns0 - ps) + expf(ns1 - ps));
            ws[b]         = mf;
            ws[BATCH + b] = rg;
        }
    }
}

// Deterministic final reduction: one block, fixed tree.
__global__ __launch_bounds__(256) void mixgcf_reduce(const float* __restrict__ ws,
                                                     float* __restrict__ out)
{
    __shared__ float smf[256];
    __shared__ float srg[256];
    const int t = threadIdx.x;
    float mf = 0.f, rg = 0.f;
    #pragma unroll
    for (int i = 0; i < BATCH / 256; ++i) {
        mf += ws[t + i * 256];
        rg += ws[BATCH + t + i * 256];
    }
    smf[t] = mf; srg[t] = rg;
    __syncthreads();
    for (int s = 128; s > 0; s >>= 1) {
        if (t < s) { smf[t] += smf[t + s]; srg[t] += srg[t + s]; }
        __syncthreads();
    }
    if (t == 0) {
        const float mf_loss  = smf[0] / (float)BATCH;
        const float emb_loss = DECAY * (srg[0] * 0.5f) / (float)BATCH;
        out[0] = mf_loss + emb_loss;
        out[1] = mf_loss;
        out[2] = emb_loss;
    }
}

extern "C" void kernel_launch(void* const* d_in, const int* in_sizes, int n_in,
                              void* d_out, int out_size, void* d_ws, size_t ws_size,
                              hipStream_t stream)
{
    const float* user_emb  = (const float*)d_in[0];
    const float* item_emb  = (const float*)d_in[1];
    const float* seed      = (const float*)d_in[2];
    const int*   user      = (const int*)d_in[3];
    const int*   pos_item  = (const int*)d_in[4];
    const int*   neg_item  = (const int*)d_in[5];
    float* ws  = (float*)d_ws;
    float* out = (float*)d_out;

    mixgcf_main<<<BATCH, 256, 0, stream>>>(user_emb, item_emb, seed,
                                           user, pos_item, neg_item, ws);
    mixgcf_reduce<<<1, 256, 0, stream>>>(ws, out);
}